// Round 7
// baseline (83.878 us; speedup 1.0000x reference)
//
#include <hip/hip_runtime.h>

namespace {

constexpr int HIMG = 512;
constexpr int ROWF = 512 * 3;            // 1536 floats per image row
constexpr int NT   = 384;                // one float4 column per thread
constexpr int RCH  = 4;                  // output rows per block
constexpr int NLOAD = RCH + 6;           // 10 input rows per block
constexpr int HALO = 12;                 // halo floats each side (16B aligned)
constexpr int RP   = HALO + ROWF + HALO; // 1560 floats per LDS row
constexpr int CHUNKS = HIMG / RCH;       // 128 chunks per image
constexpr int NGRP = ROWF / 8;           // 192 eight-float groups per row

typedef float vf4 __attribute__((ext_vector_type(4)));

// exp(-x^2/(2*1.5^2)), double precision (matches cv2.getGaussianKernel)
constexpr double KD0 = 0.13533528323661270;  // x=3
constexpr double KD1 = 0.41111229050718745;  // x=2
constexpr double KD2 = 0.80073740291680804;  // x=1
constexpr double KSUM = 1.0 + 2.0 * (KD0 + KD1 + KD2);

__global__ __launch_bounds__(NT, 6) void gauss7(const float* __restrict__ in,
                                                float* __restrict__ out) {
  constexpr float W[7] = {
      (float)(KD0 / KSUM), (float)(KD1 / KSUM), (float)(KD2 / KSUM),
      (float)(1.0 / KSUM),
      (float)(KD2 / KSUM), (float)(KD1 / KSUM), (float)(KD0 / KSUM)};

  __shared__ __align__(16) float lds[RCH][RP];

  // bijective XCD swizzle: 8192 blocks, 8 XCDs -> XCD k owns contiguous 1024
  const int bid = blockIdx.x;
  const int b   = (bid & 7) * (CHUNKS * 64 / 8) + (bid >> 3);

  const int n  = b >> 7;        // image index (128 chunks per image)
  const int hc = b & 127;
  const int h0 = hc * RCH;
  const int t  = threadIdx.x;

  const float* inN  = in  + (size_t)n * HIMG * ROWF;
  float*       outN = out + (size_t)n * HIMG * ROWF;
  const float4* inCol = reinterpret_cast<const float4*>(inN) + t;  // row stride = 384 float4

  // ---- issue ALL 10 row loads (reflect-101 in H) ----
  float4 rw[NLOAD];
#pragma unroll
  for (int i = 0; i < NLOAD; ++i) {
    int r  = h0 - 3 + i;
    int rr = r < 0 ? -r : (r > HIMG - 1 ? 2 * (HIMG - 1) - r : r);
    rw[i]  = inCol[(size_t)rr * NT];
  }

  // ---- vertical blur, accumulator form (same summation order: j=0..6) ----
  float4 acc[RCH];
#pragma unroll
  for (int o = 0; o < RCH; ++o) acc[o] = make_float4(0.f, 0.f, 0.f, 0.f);
#pragma unroll
  for (int i = 0; i < NLOAD; ++i) {
#pragma unroll
    for (int o = 0; o < RCH; ++o) {
      if (i >= o && i <= o + 6) {
        const float w = W[i - o];
        acc[o].x += w * rw[i].x;
        acc[o].y += w * rw[i].y;
        acc[o].z += w * rw[i].z;
        acc[o].w += w * rw[i].w;
      }
    }
  }

  // ---- stage to LDS with reflect-101 W-halo (verified mapping, R2/R4/R5) ----
#pragma unroll
  for (int i = 0; i < RCH; ++i) {
    const float4 v = acc[i];
    float* lrow = &lds[i][HALO];
    *reinterpret_cast<float4*>(lrow + 4 * t) = v;   // 16B-aligned, conflict-free

    if (t == 0) {                  // floats 0..3
      lrow[-3] = v.w;              // f3  (p1,c0) -> -3
    } else if (t == 1) {           // floats 4..7
      lrow[-2] = v.x; lrow[-1] = v.y; lrow[-6] = v.z; lrow[-5] = v.w;
    } else if (t == 2) {           // floats 8..11
      lrow[-4] = v.x; lrow[-9] = v.y; lrow[-8] = v.z; lrow[-7] = v.w;
    } else if (t == NT - 3) {      // floats 1524..1527
      lrow[1542] = v.x; lrow[1543] = v.y; lrow[1544] = v.z; lrow[1539] = v.w;
    } else if (t == NT - 2) {      // floats 1528..1531
      lrow[1540] = v.x; lrow[1541] = v.y; lrow[1536] = v.z; lrow[1537] = v.w;
    } else if (t == NT - 1) {      // floats 1532..1535
      lrow[1538] = v.x;
    }
  }
  __syncthreads();

  // ---- horizontal pass: 8-float groups, 2 tasks/thread ----
  // thread t -> group g of rows {r2, r2+2}, r2 = t/192
  const int r2 = (t >= NGRP) ? 1 : 0;
  const int g  = t - r2 * NGRP;            // 0..191
#pragma unroll
  for (int k = 0; k < 2; ++k) {
    const int r = r2 + 2 * k;
    const float* rowp = &lds[r][HALO + 8 * g - 12];  // byte offset 32g: aligned
    float s[32];
#pragma unroll
    for (int j = 0; j < 8; ++j)
      *reinterpret_cast<float4*>(&s[4 * j]) =
          *reinterpret_cast<const float4*>(rowp + 4 * j);
    // out[8g+m] taps: s[m+3 .. m+21 step 3]
    vf4 o0, o1;
#pragma unroll
    for (int m = 0; m < 4; ++m) {
      o0[m] = W[0]*s[m+3]  + W[1]*s[m+6]  + W[2]*s[m+9]  + W[3]*s[m+12] +
              W[4]*s[m+15] + W[5]*s[m+18] + W[6]*s[m+21];
      o1[m] = W[0]*s[m+7]  + W[1]*s[m+10] + W[2]*s[m+13] + W[3]*s[m+16] +
              W[4]*s[m+19] + W[5]*s[m+22] + W[6]*s[m+25];
    }
    float* orow = outN + (size_t)(h0 + r) * ROWF + 8 * g;
    __builtin_nontemporal_store(o0, reinterpret_cast<vf4*>(orow));
    __builtin_nontemporal_store(o1, reinterpret_cast<vf4*>(orow + 4));
  }
}

}  // namespace

extern "C" void kernel_launch(void* const* d_in, const int* in_sizes, int n_in,
                              void* d_out, int out_size, void* d_ws, size_t ws_size,
                              hipStream_t stream) {
  const float* x = (const float*)d_in[0];
  float*       y = (float*)d_out;
  dim3 grid(64 * CHUNKS);   // 8192 blocks
  dim3 block(NT);
  hipLaunchKernelGGL(gauss7, grid, block, 0, stream, x, y);
}

// Round 8
// 63.931 us; speedup vs baseline: 1.3120x; 1.3120x over previous
//
#include <hip/hip_runtime.h>

namespace {

constexpr int HIMG = 512;
constexpr int ROWF = 512 * 3;            // 1536 floats per image row
constexpr int NT   = 384;                // one float4 column per thread
constexpr int RCH  = 4;                  // output rows per block
constexpr int NLOAD = RCH + 6;           // 10 input rows per block
constexpr int HALO = 12;                 // halo floats each side (16B aligned)
constexpr int RP   = HALO + ROWF + HALO; // 1560 floats per LDS row
constexpr int CHUNKS = HIMG / RCH;       // 128 chunks per image

typedef float vf4 __attribute__((ext_vector_type(4)));

// exp(-x^2/(2*1.5^2)), double precision (matches cv2.getGaussianKernel)
constexpr double KD0 = 0.13533528323661270;  // x=3
constexpr double KD1 = 0.41111229050718745;  // x=2
constexpr double KD2 = 0.80073740291680804;  // x=1
constexpr double KSUM = 1.0 + 2.0 * (KD0 + KD1 + KD2);

// DPP lane-shift within 16-lane rows; invalid lanes keep `oldv` (bound_ctrl=0).
// row_shr:k = 0x110+k (dst lane l <- l-k), row_shl:k = 0x100+k (dst <- l+k).
template <int CTRL>
__device__ __forceinline__ float4 dpp4(float4 oldv, float4 src) {
  float4 r;
  r.x = __builtin_bit_cast(float, __builtin_amdgcn_update_dpp(
      __builtin_bit_cast(int, oldv.x), __builtin_bit_cast(int, src.x), CTRL, 0xF, 0xF, false));
  r.y = __builtin_bit_cast(float, __builtin_amdgcn_update_dpp(
      __builtin_bit_cast(int, oldv.y), __builtin_bit_cast(int, src.y), CTRL, 0xF, 0xF, false));
  r.z = __builtin_bit_cast(float, __builtin_amdgcn_update_dpp(
      __builtin_bit_cast(int, oldv.z), __builtin_bit_cast(int, src.z), CTRL, 0xF, 0xF, false));
  r.w = __builtin_bit_cast(float, __builtin_amdgcn_update_dpp(
      __builtin_bit_cast(int, oldv.w), __builtin_bit_cast(int, src.w), CTRL, 0xF, 0xF, false));
  return r;
}

__global__ __launch_bounds__(NT, 5) void gauss7(const float* __restrict__ in,
                                                float* __restrict__ out) {
  constexpr float W[7] = {
      (float)(KD0 / KSUM), (float)(KD1 / KSUM), (float)(KD2 / KSUM),
      (float)(1.0 / KSUM),
      (float)(KD2 / KSUM), (float)(KD1 / KSUM), (float)(KD0 / KSUM)};

  __shared__ __align__(16) float lds[RCH][RP];

  // bijective XCD swizzle: 8192 blocks, 8 XCDs
  const int bid = blockIdx.x;
  const int b   = (bid & 7) * (CHUNKS * 64 / 8) + (bid >> 3);

  const int n  = b >> 7;
  const int hc = b & 127;
  const int h0 = hc * RCH;
  const int t  = threadIdx.x;

  const float* inN  = in  + (size_t)n * HIMG * ROWF;
  float*       outN = out + (size_t)n * HIMG * ROWF;
  const float4* inCol = reinterpret_cast<const float4*>(inN) + t;

  // ---- issue ALL 10 row loads (reflect-101 in H), pinned before compute ----
  float4 rw[NLOAD];
#pragma unroll
  for (int i = 0; i < NLOAD; ++i) {
    int r  = h0 - 3 + i;
    int rr = r < 0 ? -r : (r > HIMG - 1 ? 2 * (HIMG - 1) - r : r);
    rw[i]  = inCol[(size_t)rr * NT];
  }
  __builtin_amdgcn_sched_barrier(0);   // force all 10 loads in flight (MLP)

  // ---- vertical blur, accumulator form (summation order j=0..6, as verified) ----
  float4 acc[RCH];
#pragma unroll
  for (int o = 0; o < RCH; ++o) acc[o] = make_float4(0.f, 0.f, 0.f, 0.f);
#pragma unroll
  for (int i = 0; i < NLOAD; ++i) {
#pragma unroll
    for (int o = 0; o < RCH; ++o) {
      if (i >= o && i <= o + 6) {
        const float w = W[i - o];
        acc[o].x += w * rw[i].x;
        acc[o].y += w * rw[i].y;
        acc[o].z += w * rw[i].z;
        acc[o].w += w * rw[i].w;
      }
    }
  }

  // ---- stage to LDS (cross-wave patches + image-edge halo), verified mapping ----
#pragma unroll
  for (int i = 0; i < RCH; ++i) {
    const float4 v = acc[i];
    float* lrow = &lds[i][HALO];
    *reinterpret_cast<float4*>(lrow + 4 * t) = v;

    if (t == 0) {                  // floats 0..3
      lrow[-3] = v.w;
    } else if (t == 1) {           // floats 4..7
      lrow[-2] = v.x; lrow[-1] = v.y; lrow[-6] = v.z; lrow[-5] = v.w;
    } else if (t == 2) {           // floats 8..11
      lrow[-4] = v.x; lrow[-9] = v.y; lrow[-8] = v.z; lrow[-7] = v.w;
    } else if (t == NT - 3) {      // floats 1524..1527
      lrow[1542] = v.x; lrow[1543] = v.y; lrow[1544] = v.z; lrow[1539] = v.w;
    } else if (t == NT - 2) {      // floats 1528..1531
      lrow[1540] = v.x; lrow[1541] = v.y; lrow[1536] = v.z; lrow[1537] = v.w;
    } else if (t == NT - 1) {      // floats 1532..1535
      lrow[1538] = v.x;
    }
  }
  __syncthreads();

  // ---- horizontal pass: neighbor chunks via DPP; 16-lane-row boundaries from LDS ----
  const int lm = t & 15;
#pragma unroll
  for (int i = 0; i < RCH; ++i) {
    const float4 v = acc[i];
    const float* base = &lds[i][HALO];   // chunk c = floats 4c..4c+3 (c in [-3, 386])
    float4 pL1 = v, pL2 = v, pL3 = v, pR1 = v, pR2 = v, pR3 = v;
    if (lm < 1)   pL1 = *reinterpret_cast<const float4*>(base + 4 * (t - 1));
    if (lm < 2)   pL2 = *reinterpret_cast<const float4*>(base + 4 * (t - 2));
    if (lm < 3)   pL3 = *reinterpret_cast<const float4*>(base + 4 * (t - 3));
    if (lm >= 15) pR1 = *reinterpret_cast<const float4*>(base + 4 * (t + 1));
    if (lm >= 14) pR2 = *reinterpret_cast<const float4*>(base + 4 * (t + 2));
    if (lm >= 13) pR3 = *reinterpret_cast<const float4*>(base + 4 * (t + 3));

    const float4 cm1 = dpp4<0x111>(pL1, v);   // chunk t-1
    const float4 cm2 = dpp4<0x112>(pL2, v);   // chunk t-2
    const float4 cm3 = dpp4<0x113>(pL3, v);   // chunk t-3
    const float4 cp1 = dpp4<0x101>(pR1, v);   // chunk t+1
    const float4 cp2 = dpp4<0x102>(pR2, v);   // chunk t+2
    const float4 cp3 = dpp4<0x103>(pR3, v);   // chunk t+3

    // s[j] = vertically-blurred float (4t - 12 + j)
    float s[28];
    s[0]=cm3.x;  s[1]=cm3.y;  s[2]=cm3.z;  s[3]=cm3.w;
    s[4]=cm2.x;  s[5]=cm2.y;  s[6]=cm2.z;  s[7]=cm2.w;
    s[8]=cm1.x;  s[9]=cm1.y;  s[10]=cm1.z; s[11]=cm1.w;
    s[12]=v.x;   s[13]=v.y;   s[14]=v.z;   s[15]=v.w;
    s[16]=cp1.x; s[17]=cp1.y; s[18]=cp1.z; s[19]=cp1.w;
    s[20]=cp2.x; s[21]=cp2.y; s[22]=cp2.z; s[23]=cp2.w;
    s[24]=cp3.x; s[25]=cp3.y; s[26]=cp3.z; s[27]=cp3.w;

    vf4 o;
#pragma unroll
    for (int m = 0; m < 4; ++m)
      o[m] = W[0]*s[m+3]  + W[1]*s[m+6]  + W[2]*s[m+9]  + W[3]*s[m+12] +
             W[4]*s[m+15] + W[5]*s[m+18] + W[6]*s[m+21];

    __builtin_nontemporal_store(
        o, reinterpret_cast<vf4*>(outN + (size_t)(h0 + i) * ROWF) + t);
  }
}

}  // namespace

extern "C" void kernel_launch(void* const* d_in, const int* in_sizes, int n_in,
                              void* d_out, int out_size, void* d_ws, size_t ws_size,
                              hipStream_t stream) {
  const float* x = (const float*)d_in[0];
  float*       y = (float*)d_out;
  dim3 grid(64 * CHUNKS);   // 8192 blocks
  dim3 block(NT);
  hipLaunchKernelGGL(gauss7, grid, block, 0, stream, x, y);
}